// Round 15
// baseline (28.745 us; speedup 1.0000x reference)
//
#include <hip/hip_runtime.h>

// DiffNet, single dispatch, 3 phases, 4 domains x 32 blocks x 512 threads.
// Same per-wave shape as the best measured kernel (R8/R14: ROWS=8, CPW=2,
// register-resident weights) but HALF the blocks: 128 x 512thr instead of
// 256 x 256thr. Targets dispatch/start skew (absorbed by barrier 1) and
// arrival population (32 vs 64). Everything else proven: fused stage+s1/s2,
// L3-atomic t1/t2 exchange, monotonic self-cleaning counters, weight
// prefetch inside the arrive->wait window.
// Math (exact collapse of the two 1x1 convs -- affine in meta):
//   Wv = vi @ W.T (pre-bias), vj = relu(Wv + b)
//   A_c = sum_h c2w[h]*c1w[h][c],  D = sum_h c2w[h]*c1b[h] + c2b
//   s1 = sum_i vi, s2 = sum_i vi^2 (per row)
//   delta = scale*(A0*s2 + A1*Wv + (A2*vj + D)*s1),  out = vj + delta

#define NDOM 4
#define BPD  32                    // blocks per domain = arrivals per barrier
#define NBLK (NDOM * BPD)          // 128

__device__ unsigned int g_cnt[NDOM * 32];    // arrival counters, 128B apart
__device__ unsigned int g_flag[NDOM * 32];   // epoch flags, 128B apart

__device__ __forceinline__ void bar_arrive(int dom, unsigned int target) {
    __syncthreads();
    if (threadIdx.x == 0) {
        asm volatile("s_waitcnt vmcnt(0)" ::: "memory");
        unsigned int old = __hip_atomic_fetch_add(&g_cnt[dom * 32], 1u,
                               __ATOMIC_RELAXED, __HIP_MEMORY_SCOPE_AGENT);
        if ((old & (BPD - 1u)) == (BPD - 1u))
            __hip_atomic_store(&g_flag[dom * 32], target,      // single writer
                               __ATOMIC_RELAXED, __HIP_MEMORY_SCOPE_AGENT);
    }
}

__device__ __forceinline__ void bar_wait(int dom, unsigned int target) {
    if (threadIdx.x == 0) {
        while ((int)(__hip_atomic_load(&g_flag[dom * 32], __ATOMIC_RELAXED,
                                       __HIP_MEMORY_SCOPE_AGENT) - target) < 0)
            __builtin_amdgcn_s_sleep(1);
        asm volatile("" ::: "memory");
    }
    __syncthreads();
}

#define KEEP4(v) asm volatile("" :: "v"((v).x), "v"((v).y), "v"((v).z), "v"((v).w))
#define KEEP1(v) asm volatile("" :: "v"(v))

// 8 rows staged in LDS by 8 waves (wave w -> row w), s1/s2 fused into staging.
// CPW (1 or 2) columns per wave, weights register-resident.
// AIN:  stage via relaxed agent atomic u64 loads (L3-coherent)
// AOUT: write via relaxed agent atomic f32 stores
template<int IIN, int OUT, int CPW, bool AIN, bool AOUT>
__device__ __forceinline__ void phase(const float* __restrict__ vin,   // [.., IIN]
                                      const float4 (&wr)[CPW][IIN / 256],
                                      const float (&bs)[CPW],
                                      float* __restrict__ vout,        // [32, OUT]
                                      float* __restrict__ lds,
                                      float* __restrict__ s1s,
                                      float* __restrict__ s2s,
                                      int rows0, int c0, int lane, int wave,
                                      float A0, float A1, float A2,
                                      float Dd, float scale)
{
    constexpr int ROWS = 8;

    // ---- fused stage + s1/s2: wave w stages row w ----
    {
        const int row = wave;
        float p1 = 0.f, p2 = 0.f;
        if (AIN) {
            const unsigned long long* src = reinterpret_cast<const unsigned long long*>(
                vin + (size_t)(rows0 + row) * IIN);
            float2* dst = reinterpret_cast<float2*>(lds + row * IIN);
            #pragma unroll
            for (int k = 0; k < IIN / 128; ++k) {
                unsigned long long u = __hip_atomic_load(&src[k * 64 + lane],
                                           __ATOMIC_RELAXED, __HIP_MEMORY_SCOPE_AGENT);
                float2 f;
                __builtin_memcpy(&f, &u, 8);
                dst[k * 64 + lane] = f;
                p1 += f.x + f.y;
                p2 += f.x * f.x + f.y * f.y;
            }
        } else {
            const float4* src = reinterpret_cast<const float4*>(
                vin + (size_t)(rows0 + row) * IIN);
            float4* dst = reinterpret_cast<float4*>(lds + row * IIN);
            #pragma unroll
            for (int k = 0; k < IIN / 256; ++k) {
                const float4 a = src[k * 64 + lane];
                dst[k * 64 + lane] = a;
                p1 += (a.x + a.y) + (a.z + a.w);
                p2 += a.x * a.x + a.y * a.y + a.z * a.z + a.w * a.w;
            }
        }
        #pragma unroll
        for (int s = 32; s > 0; s >>= 1) {
            p1 += __shfl_xor(p1, s);
            p2 += __shfl_xor(p2, s);
        }
        if (lane == 0) { s1s[row] = p1; s2s[row] = p2; }
    }
    __syncthreads();   // covers staged rows AND s1s/s2s

    // ---- dots: CPW columns per wave vs 8 staged rows ----
    float acc[CPW][ROWS];
    #pragma unroll
    for (int c = 0; c < CPW; ++c)
        #pragma unroll
        for (int r = 0; r < ROWS; ++r) acc[c][r] = 0.f;

    #pragma unroll
    for (int q = 0; q < IIN / 256; ++q) {
        float4 w[CPW];
        #pragma unroll
        for (int c = 0; c < CPW; ++c) w[c] = wr[c][q];
        #pragma unroll
        for (int r = 0; r < ROWS; ++r) {
            const float4 v4 = *reinterpret_cast<const float4*>(
                lds + r * IIN + (q * 64 + lane) * 4);
            #pragma unroll
            for (int c = 0; c < CPW; ++c)
                acc[c][r] = fmaf(w[c].w, v4.w, fmaf(w[c].z, v4.z,
                            fmaf(w[c].y, v4.y, fmaf(w[c].x, v4.x, acc[c][r]))));
        }
    }

    // ---- reduce ----
    float Wv = 0.f;
    #pragma unroll
    for (int r = 0; r < ROWS; ++r) {
        if (CPW == 2) {
            const float u = acc[0][r] + __shfl_xor(acc[0][r], 1);
            const float w = acc[CPW - 1][r] + __shfl_xor(acc[CPW - 1][r], 1);
            float z = (lane & 1) ? w : u;
            #pragma unroll
            for (int s = 2; s < 64; s <<= 1) z += __shfl_xor(z, s);
            if ((lane >> 1) == r) Wv = z;    // even lane: col c0, odd: c0+1
        } else {
            float z = acc[0][r];
            #pragma unroll
            for (int s = 1; s < 64; s <<= 1) z += __shfl_xor(z, s);
            if (lane == r) Wv = z;           // lane r: col c0
        }
    }

    // ---- epilogue (s1s/s2s covered by the staging barrier) ----
    if (lane < ROWS * CPW) {
        const int row = (CPW == 2) ? (lane >> 1) : lane;
        const int cc  = (CPW == 2) ? (lane & 1) : 0;
        const float biasv = (CPW == 2) ? ((lane & 1) ? bs[CPW - 1] : bs[0]) : bs[0];
        const float vj  = fmaxf(Wv + biasv, 0.f);
        const float val = vj + scale * (A0 * s2s[row] + A1 * Wv
                                        + (A2 * vj + Dd) * s1s[row]);
        float* dst = vout + (size_t)(rows0 + row) * OUT + c0 + cc;
        if (AOUT)
            __hip_atomic_store(dst, val, __ATOMIC_RELAXED, __HIP_MEMORY_SCOPE_AGENT);
        else
            *dst = val;
    }
}

__global__ void __launch_bounds__(512, 1)
diffnet_onekernel(const float* __restrict__ x,
                  const float* __restrict__ W1, const float* __restrict__ b1,
                  const float* __restrict__ W2, const float* __restrict__ b2,
                  const float* __restrict__ W3, const float* __restrict__ b3,
                  const float* __restrict__ c1w, const float* __restrict__ c1b,
                  const float* __restrict__ c2w, const float* __restrict__ c2b,
                  const int* __restrict__ bn,
                  float* __restrict__ t1, float* __restrict__ t2,
                  float* __restrict__ out)
{
    __shared__ float lds[8 * 1024];       // 32 KB (phase 1: 8 rows x 1024)
    __shared__ float s1s[8], s2s[8];

    const int bid  = blockIdx.x;
    const int dom  = bid >> 5;            // 4 domains x 32 blocks
    const int j    = bid & 31;
    const int rows0 = dom * 8;
    const int lane = threadIdx.x & 63;
    const int wave = threadIdx.x >> 6;    // 0..7

    // epoch base (safe: this domain's flag can't advance until this block
    // itself arrives at barrier 1)
    unsigned int F0 = 0;
    if (threadIdx.x == 0)
        F0 = __hip_atomic_load(&g_flag[dom * 32], __ATOMIC_RELAXED,
                               __HIP_MEMORY_SCOPE_AGENT);

    // collapsed conv constants (uniform scalar loads)
    float A0 = 0.f, A1 = 0.f, A2 = 0.f, Dd = c2b[0];
    #pragma unroll
    for (int h = 0; h < 8; ++h) {
        const float w2 = c2w[h];
        A0 = fmaf(w2, c1w[h * 3 + 0], A0);
        A1 = fmaf(w2, c1w[h * 3 + 1], A1);
        A2 = fmaf(w2, c1w[h * 3 + 2], A2);
        Dd = fmaf(w2, c1b[h], Dd);
    }
    const int raw = bn[0];
    const float bnf = (raw > 0 && raw < 1000000) ? (float)raw : __int_as_float(raw);
    const float scale = 0.1f / bnf;

    const int c12 = j * 16 + wave * 2;    // phases 1/2: 16 cols/block, 2/wave
    const int c3  = j * 8  + wave;        // phase 3:     8 cols/block, 1/wave

    // ---- prefetch phase-1 weights (overlaps x staging) ----
    float4 w1r[2][4];
    float  b1s[2];
    {
        #pragma unroll
        for (int cc = 0; cc < 2; ++cc) {
            const float4* Wr = reinterpret_cast<const float4*>(W1 + (size_t)(c12 + cc) * 1024);
            #pragma unroll
            for (int q = 0; q < 4; ++q) w1r[cc][q] = Wr[q * 64 + lane];
            b1s[cc] = b1[c12 + cc];
        }
    }

    // phase 1: x[8 rows,1024] -> t1[8 rows,512]
    phase<1024, 512, 2, false, true>(x, w1r, b1s, t1, lds, s1s, s2s,
                                     rows0, c12, lane, wave,
                                     A0, A1, A2, Dd, scale);
    bar_arrive(dom, F0 + 1);   // announce immediately (data stores drained)

    // ---- prefetch phase-2 weights INSIDE the arrive->wait window ----
    float4 w2r[2][2];
    float  b2s[2];
    {
        #pragma unroll
        for (int cc = 0; cc < 2; ++cc) {
            const float4* Wr = reinterpret_cast<const float4*>(W2 + (size_t)(c12 + cc) * 512);
            #pragma unroll
            for (int q = 0; q < 2; ++q) w2r[cc][q] = Wr[q * 64 + lane];
            b2s[cc] = b2[c12 + cc];
        }
    }
    KEEP4(w2r[0][0]); KEEP4(w2r[0][1]); KEEP4(w2r[1][0]); KEEP4(w2r[1][1]);
    KEEP1(b2s[0]); KEEP1(b2s[1]);

    bar_wait(dom, F0 + 1);

    // phase 2: t1 -> t2[8 rows,512]
    phase<512, 512, 2, true, true>(t1, w2r, b2s, t2, lds, s1s, s2s,
                                   rows0, c12, lane, wave,
                                   A0, A1, A2, Dd, scale);
    bar_arrive(dom, F0 + 2);

    // ---- prefetch phase-3 weights INSIDE the arrive->wait window ----
    float4 w3r[1][2];
    float  b3s[1];
    {
        const float4* Wr = reinterpret_cast<const float4*>(W3 + (size_t)c3 * 512);
        #pragma unroll
        for (int q = 0; q < 2; ++q) w3r[0][q] = Wr[q * 64 + lane];
        b3s[0] = b3[c3];
    }
    KEEP4(w3r[0][0]); KEEP4(w3r[0][1]);
    KEEP1(b3s[0]);

    bar_wait(dom, F0 + 2);

    // phase 3: t2 -> out[8 rows,256] (plain stores)
    phase<512, 256, 1, true, false>(t2, w3r, b3s, out, lds, s1s, s2s,
                                    rows0, c3, lane, wave,
                                    A0, A1, A2, Dd, scale);
}

extern "C" void kernel_launch(void* const* d_in, const int* in_sizes, int n_in,
                              void* d_out, int out_size, void* d_ws, size_t ws_size,
                              hipStream_t stream) {
    const float* x     = (const float*)d_in[0];
    const float* fc1_w = (const float*)d_in[1];
    const float* fc1_b = (const float*)d_in[2];
    const float* fc2_w = (const float*)d_in[3];
    const float* fc2_b = (const float*)d_in[4];
    const float* fc3_w = (const float*)d_in[5];
    const float* fc3_b = (const float*)d_in[6];
    const float* c1w   = (const float*)d_in[7];
    const float* c1b   = (const float*)d_in[8];
    const float* c2w   = (const float*)d_in[9];
    const float* c2b   = (const float*)d_in[10];
    const int*   bn    = (const int*)d_in[11];

    float* t1  = (float*)d_ws;                         // [32, 512] = 64KB
    float* t2  = t1 + 32 * 512;                        // [32, 512] = 64KB
    float* out = (float*)d_out;                        // [32, 256]

    diffnet_onekernel<<<dim3(NBLK), dim3(512), 0, stream>>>(
        x, fc1_w, fc1_b, fc2_w, fc2_b, fc3_w, fc3_b,
        c1w, c1b, c2w, c2b, bn, t1, t2, out);
}

// Round 16
// 21.395 us; speedup vs baseline: 1.3436x; 1.3436x over previous
//
#include <hip/hip_runtime.h>

// DiffNet, single dispatch, 3 phases, 4 domains x 64 blocks x 256 threads --
// the best-measured configuration (R8/R13/R14 plateau: 21.3-21.6us).
// Empirical record: 512-thread blocks +7us (R12/R15); dual-stream +19us (R9);
// 2 blocks/CU oversubscription pathological (R10); CPW=4 weight arrays get
// rematerialized (R11). This is the measured optimum.
//
// Math (exact collapse of the two 1x1 convs -- affine in meta, no
// nonlinearity between them):
//   Wv = vi @ W.T (pre-bias), vj = relu(Wv + b)
//   A_c = sum_h c2w[h]*c1w[h][c],  D = sum_h c2w[h]*c1b[h] + c2b
//   s1 = sum_i vi, s2 = sum_i vi^2 (per row)
//   delta = scale*(A0*s2 + A1*Wv + (A2*vj + D)*s1),  out = vj + delta
//
// Structure: 4 row-domains x 8 batch rows, 64 blocks each. Inter-phase t1/t2
// exchanged via relaxed AGENT-scope atomics (coherent at L3; NO cache fences
// anywhere -- __threadfence's L2 writeback/invalidate cost ~10us/barrier,
// measured R5->R6). Barrier: hierarchical monotonic counters (8 groups of 8
// -> domain counter -> epoch flag) in zero-init __device__ globals;
// self-cleaning (invariants mod 8 preserved across launches), no reset node,
// deterministic across graph replays. s1/s2 fused into the staging loop
// (values already in registers). Next-layer weight prefetch issues inside
// the arrive->wait window so HBM latency hides under the spin.

#define NDOM 4
#define BPD  64                    // blocks per domain
#define NBLK (NDOM * BPD)          // 256

__device__ unsigned int g_grp[NDOM * 8 * 32];   // 8 group counters/domain, 128B apart
__device__ unsigned int g_cnt[NDOM * 32];       // domain closer counters
__device__ unsigned int g_flag[NDOM * 32];      // epoch flags

__device__ __forceinline__ void bar_arrive(int dom, int j, unsigned int target) {
    __syncthreads();   // compiler drains each wave's vmem before s_barrier
    if (threadIdx.x == 0) {
        asm volatile("s_waitcnt vmcnt(0)" ::: "memory");
        unsigned int p = __hip_atomic_fetch_add(&g_grp[(dom * 8 + (j >> 3)) * 32], 1u,
                             __ATOMIC_RELAXED, __HIP_MEMORY_SCOPE_AGENT);
        if ((p & 7u) == 7u) {
            unsigned int q = __hip_atomic_fetch_add(&g_cnt[dom * 32], 1u,
                                 __ATOMIC_RELAXED, __HIP_MEMORY_SCOPE_AGENT);
            if ((q & 7u) == 7u)
                __hip_atomic_store(&g_flag[dom * 32], target,   // single writer
                                   __ATOMIC_RELAXED, __HIP_MEMORY_SCOPE_AGENT);
        }
    }
}

__device__ __forceinline__ void bar_wait(int dom, unsigned int target) {
    if (threadIdx.x == 0) {
        while ((int)(__hip_atomic_load(&g_flag[dom * 32], __ATOMIC_RELAXED,
                                       __HIP_MEMORY_SCOPE_AGENT) - target) < 0)
            __builtin_amdgcn_s_sleep(1);
        asm volatile("" ::: "memory");
    }
    __syncthreads();
}

#define KEEP4(v) asm volatile("" :: "v"((v).x), "v"((v).y), "v"((v).z), "v"((v).w))
#define KEEP1(v) asm volatile("" :: "v"(v))

// AIN:  stage input via relaxed agent atomic u64 loads (L3-coherent)
// AOUT: write output via relaxed agent atomic f32 stores
template<int IIN, int OUT, int ROWS, int CPB, bool AIN, bool AOUT>
__device__ __forceinline__ void phase(const float* __restrict__ vin,   // [.., IIN]
                                      const float4 (&wr)[2][IIN / 256],
                                      float b0, float b1,
                                      float* __restrict__ vout,        // [32, OUT]
                                      float* __restrict__ lds,
                                      float* __restrict__ s1s,
                                      float* __restrict__ s2s,
                                      int rows0, int c0, int lane, int wave,
                                      float A0, float A1, float A2,
                                      float Dd, float scale)
{
    constexpr int RPW = ROWS / 4;    // rows per wave (2)

    // ---- fused stage + s1/s2: wave w stages rows {w*RPW..}, accumulating s ----
    #pragma unroll
    for (int r = 0; r < RPW; ++r) {
        const int row = wave * RPW + r;
        float p1 = 0.f, p2 = 0.f;
        if (AIN) {
            const unsigned long long* src = reinterpret_cast<const unsigned long long*>(
                vin + (size_t)(rows0 + row) * IIN);
            float2* dst = reinterpret_cast<float2*>(lds + row * IIN);
            #pragma unroll
            for (int k = 0; k < IIN / 128; ++k) {
                unsigned long long u = __hip_atomic_load(&src[k * 64 + lane],
                                           __ATOMIC_RELAXED, __HIP_MEMORY_SCOPE_AGENT);
                float2 f;
                __builtin_memcpy(&f, &u, 8);
                dst[k * 64 + lane] = f;
                p1 += f.x + f.y;
                p2 += f.x * f.x + f.y * f.y;
            }
        } else {
            const float4* src = reinterpret_cast<const float4*>(
                vin + (size_t)(rows0 + row) * IIN);
            float4* dst = reinterpret_cast<float4*>(lds + row * IIN);
            #pragma unroll
            for (int k = 0; k < IIN / 256; ++k) {
                const float4 a = src[k * 64 + lane];
                dst[k * 64 + lane] = a;
                p1 += (a.x + a.y) + (a.z + a.w);
                p2 += a.x * a.x + a.y * a.y + a.z * a.z + a.w * a.w;
            }
        }
        #pragma unroll
        for (int s = 32; s > 0; s >>= 1) {
            p1 += __shfl_xor(p1, s);
            p2 += __shfl_xor(p2, s);
        }
        if (lane == 0) { s1s[row] = p1; s2s[row] = p2; }
    }
    __syncthreads();   // covers staged rows AND s1s/s2s

    // ---- dots: 2 columns per wave vs ROWS staged rows ----
    float acc0[ROWS], acc1[ROWS];
    #pragma unroll
    for (int r = 0; r < ROWS; ++r) { acc0[r] = 0.f; acc1[r] = 0.f; }

    #pragma unroll
    for (int q = 0; q < IIN / 256; ++q) {
        const float4 w0 = wr[0][q];
        const float4 w1 = wr[1][q];
        #pragma unroll
        for (int r = 0; r < ROWS; ++r) {
            const float4 v4 = *reinterpret_cast<const float4*>(
                lds + r * IIN + (q * 64 + lane) * 4);
            acc0[r] = fmaf(w0.w, v4.w, fmaf(w0.z, v4.z,
                      fmaf(w0.y, v4.y, fmaf(w0.x, v4.x, acc0[r]))));
            acc1[r] = fmaf(w1.w, v4.w, fmaf(w1.z, v4.z,
                      fmaf(w1.y, v4.y, fmaf(w1.x, v4.x, acc1[r]))));
        }
    }

    // ---- paired butterfly reduce: lane pair (2r, 2r+1) keeps row r's two cols ----
    float Wv = 0.f;
    #pragma unroll
    for (int r = 0; r < ROWS; ++r) {
        const float u = acc0[r] + __shfl_xor(acc0[r], 1);
        const float w = acc1[r] + __shfl_xor(acc1[r], 1);
        float z = (lane & 1) ? w : u;
        #pragma unroll
        for (int s = 2; s < 64; s <<= 1) z += __shfl_xor(z, s);
        if ((lane >> 1) == r) Wv = z;    // even lane: col c0, odd: col c0+1
    }

    // ---- epilogue (s1s/s2s already synced by the staging barrier) ----
    if (wave < CPB / 2 && lane < 2 * ROWS) {
        const int row = lane >> 1;
        const int col = c0 + (lane & 1);
        const float bias = (lane & 1) ? b1 : b0;
        const float vj  = fmaxf(Wv + bias, 0.f);
        const float val = vj + scale * (A0 * s2s[row] + A1 * Wv
                                        + (A2 * vj + Dd) * s1s[row]);
        float* dst = vout + (size_t)(rows0 + row) * OUT + col;
        if (AOUT)
            __hip_atomic_store(dst, val, __ATOMIC_RELAXED, __HIP_MEMORY_SCOPE_AGENT);
        else
            *dst = val;
    }
}

__global__ void __launch_bounds__(256, 1)
diffnet_onekernel(const float* __restrict__ x,
                  const float* __restrict__ W1, const float* __restrict__ b1,
                  const float* __restrict__ W2, const float* __restrict__ b2,
                  const float* __restrict__ W3, const float* __restrict__ b3,
                  const float* __restrict__ c1w, const float* __restrict__ c1b,
                  const float* __restrict__ c2w, const float* __restrict__ c2b,
                  const int* __restrict__ bn,
                  float* __restrict__ t1, float* __restrict__ t2,
                  float* __restrict__ out)
{
    __shared__ float lds[8 * 1024];       // 32 KB (phase 1: 8 rows x 1024)
    __shared__ float s1s[8], s2s[8];

    const int bid  = blockIdx.x;
    const int dom  = bid >> 6;            // 4 domains x 64 blocks
    const int j    = bid & 63;
    const int rows0 = dom * 8;
    const int lane = threadIdx.x & 63;
    const int wave = threadIdx.x >> 6;

    // epoch base (safe: this domain's flag can't advance until this block
    // itself arrives at barrier 1)
    unsigned int F0 = 0;
    if (threadIdx.x == 0)
        F0 = __hip_atomic_load(&g_flag[dom * 32], __ATOMIC_RELAXED,
                               __HIP_MEMORY_SCOPE_AGENT);

    // collapsed conv constants (uniform scalar loads)
    float A0 = 0.f, A1 = 0.f, A2 = 0.f, Dd = c2b[0];
    #pragma unroll
    for (int h = 0; h < 8; ++h) {
        const float w2 = c2w[h];
        A0 = fmaf(w2, c1w[h * 3 + 0], A0);
        A1 = fmaf(w2, c1w[h * 3 + 1], A1);
        A2 = fmaf(w2, c1w[h * 3 + 2], A2);
        Dd = fmaf(w2, c1b[h], Dd);
    }
    const int raw = bn[0];
    const float bnf = (raw > 0 && raw < 1000000) ? (float)raw : __int_as_float(raw);
    const float scale = 0.1f / bnf;

    const int c12 = j * 8 + wave * 2;           // phases 1/2: 8 cols/block
    const int c3  = j * 4 + (wave & 1) * 2;     // phase 3: 4 cols/block

    // ---- prefetch phase-1 weights (overlaps x staging) ----
    float4 w1r[2][4];
    {
        #pragma unroll
        for (int cc = 0; cc < 2; ++cc) {
            const float4* Wr = reinterpret_cast<const float4*>(W1 + (size_t)(c12 + cc) * 1024);
            #pragma unroll
            for (int q = 0; q < 4; ++q) w1r[cc][q] = Wr[q * 64 + lane];
        }
    }
    const float b1a = b1[c12], b1b = b1[c12 + 1];

    // phase 1: x[8 rows,1024] -> t1[8 rows,512]
    phase<1024, 512, 8, 8, false, true>(x, w1r, b1a, b1b, t1, lds, s1s, s2s,
                                        rows0, c12, lane, wave,
                                        A0, A1, A2, Dd, scale);
    bar_arrive(dom, j, F0 + 1);   // announce immediately (data stores drained)

    // ---- prefetch phase-2 weights INSIDE the arrive->wait window ----
    float4 w2r[2][2];
    {
        #pragma unroll
        for (int cc = 0; cc < 2; ++cc) {
            const float4* Wr = reinterpret_cast<const float4*>(W2 + (size_t)(c12 + cc) * 512);
            #pragma unroll
            for (int q = 0; q < 2; ++q) w2r[cc][q] = Wr[q * 64 + lane];
        }
    }
    const float b2a = b2[c12], b2b = b2[c12 + 1];
    KEEP4(w2r[0][0]); KEEP4(w2r[0][1]); KEEP4(w2r[1][0]); KEEP4(w2r[1][1]);
    KEEP1(b2a); KEEP1(b2b);

    bar_wait(dom, F0 + 1);

    // phase 2: t1 -> t2[8 rows,512]
    phase<512, 512, 8, 8, true, true>(t1, w2r, b2a, b2b, t2, lds, s1s, s2s,
                                      rows0, c12, lane, wave,
                                      A0, A1, A2, Dd, scale);
    bar_arrive(dom, j, F0 + 2);

    // ---- prefetch phase-3 weights INSIDE the arrive->wait window ----
    float4 w3r[2][2];
    {
        #pragma unroll
        for (int cc = 0; cc < 2; ++cc) {
            const float4* Wr = reinterpret_cast<const float4*>(W3 + (size_t)(c3 + cc) * 512);
            #pragma unroll
            for (int q = 0; q < 2; ++q) w3r[cc][q] = Wr[q * 64 + lane];
        }
    }
    const float b3a = b3[c3], b3b = b3[c3 + 1];
    KEEP4(w3r[0][0]); KEEP4(w3r[0][1]); KEEP4(w3r[1][0]); KEEP4(w3r[1][1]);
    KEEP1(b3a); KEEP1(b3b);

    bar_wait(dom, F0 + 2);

    // phase 3: t2 -> out[8 rows,256] (plain stores)
    phase<512, 256, 8, 4, true, false>(t2, w3r, b3a, b3b, out, lds, s1s, s2s,
                                       rows0, c3, lane, wave,
                                       A0, A1, A2, Dd, scale);
}

extern "C" void kernel_launch(void* const* d_in, const int* in_sizes, int n_in,
                              void* d_out, int out_size, void* d_ws, size_t ws_size,
                              hipStream_t stream) {
    const float* x     = (const float*)d_in[0];
    const float* fc1_w = (const float*)d_in[1];
    const float* fc1_b = (const float*)d_in[2];
    const float* fc2_w = (const float*)d_in[3];
    const float* fc2_b = (const float*)d_in[4];
    const float* fc3_w = (const float*)d_in[5];
    const float* fc3_b = (const float*)d_in[6];
    const float* c1w   = (const float*)d_in[7];
    const float* c1b   = (const float*)d_in[8];
    const float* c2w   = (const float*)d_in[9];
    const float* c2b   = (const float*)d_in[10];
    const int*   bn    = (const int*)d_in[11];

    float* t1  = (float*)d_ws;                         // [32, 512] = 64KB
    float* t2  = t1 + 32 * 512;                        // [32, 512] = 64KB
    float* out = (float*)d_out;                        // [32, 256]

    diffnet_onekernel<<<dim3(NBLK), dim3(256), 0, stream>>>(
        x, fc1_w, fc1_b, fc2_w, fc2_b, fc3_w, fc3_b,
        c1w, c1b, c2w, c2b, bn, t1, t2, out);
}